// Round 10
// baseline (208.017 us; speedup 1.0000x reference)
//
#include <hip/hip_runtime.h>
#include <hip/hip_fp16.h>

#define N_NODES 50000
#define N_EDGES 800000
#define N_FEAT 128
#define N_HIDDEN 128
#define N_CLASSES 64

#define NBUCK 256
#define BUCK_NODES 196        // ceil(50000/256)
#define BIN_CHUNK 2048
#define BIN_BLK ((N_EDGES + BIN_CHUNK - 1) / BIN_CHUNK)   // 391

#define PACK1_BLK 16
#define PACK2_BLK 8
#define PREP_BLK (BIN_BLK + PACK1_BLK + PACK2_BLK)        // 415
#define GEMM1_BLK ((N_NODES + 31) / 32)   // 1563
#define BG_BLK (BIN_BLK + GEMM1_BLK)

typedef __attribute__((ext_vector_type(8))) short bf16x8;
typedef __attribute__((ext_vector_type(4))) float f32x4;
typedef __attribute__((ext_vector_type(2))) float f32x2;

__device__ __forceinline__ unsigned short f32_to_bf16(float f) {
    unsigned int u = __float_as_uint(f);
    return (unsigned short)((u + 0x7fffu + ((u >> 16) & 1u)) >> 16);
}
__device__ __forceinline__ float bf16lo(unsigned int v) { return __uint_as_float(v << 16); }
__device__ __forceinline__ float bf16hi(unsigned int v) { return __uint_as_float(v & 0xffff0000u); }

// ---------------- fp8 helpers: HW e4m3 path, e5m2-shift fallback ----------
#if defined(__has_builtin)
#if __has_builtin(__builtin_amdgcn_cvt_pk_f32_fp8) && __has_builtin(__builtin_amdgcn_cvt_pk_fp8_f32)
#define FP8_HW 1
#endif
#endif

__device__ __forceinline__ unsigned char f32_to_fp8(float f) {
#ifdef FP8_HW
    return (unsigned char)(__builtin_amdgcn_cvt_pk_fp8_f32(f, f, 0, false) & 0xff);
#else
    unsigned short hb = __half_as_ushort(__float2half(f));
    return (unsigned char)((hb + 0x7fu + ((hb >> 8) & 1u)) >> 8);
#endif
}

__device__ __forceinline__ void fp8x4_to_f32(unsigned int u, float* o) {
#ifdef FP8_HW
    f32x2 lo = __builtin_amdgcn_cvt_pk_f32_fp8(u, false);
    f32x2 hi = __builtin_amdgcn_cvt_pk_f32_fp8(u, true);
    o[0] = lo.x; o[1] = lo.y; o[2] = hi.x; o[3] = hi.y;
#else
    o[0] = __half2float(__ushort_as_half((unsigned short)((u & 0xffu) << 8)));
    o[1] = __half2float(__ushort_as_half((unsigned short)(((u >> 8) & 0xffu) << 8)));
    o[2] = __half2float(__ushort_as_half((unsigned short)(((u >> 16) & 0xffu) << 8)));
    o[3] = __half2float(__ushort_as_half((unsigned short)(((u >> 24) & 0xffu) << 8)));
#endif
}

// ---------------------------------------------------------------------------
// Pack W helper
// ---------------------------------------------------------------------------
template <int NOUT>
__device__ void pack_w_body(int idx, const float* __restrict__ Wself,
                            const float* __restrict__ Wneigh,
                            unsigned short* __restrict__ Bp) {
    constexpr int NT = NOUT / 16;
    constexpr int NO = NOUT / 2;
    if (idx >= 4 * NT * 64) return;
    const int lane = idx & 63;
    const int tc = idx >> 6;
    const int c = tc % NT;
    const int t = tc / NT;
    const int n = c * 16 + (lane & 15);
    const int k0 = t * 32 + (lane >> 4) * 8;
    const float* W = (n < NO) ? Wself : Wneigh;
    const int nn = (n < NO) ? n : n - NO;
    ushort4 lo, hi;
    lo.x = f32_to_bf16(W[(k0 + 0) * NO + nn]);
    lo.y = f32_to_bf16(W[(k0 + 1) * NO + nn]);
    lo.z = f32_to_bf16(W[(k0 + 2) * NO + nn]);
    lo.w = f32_to_bf16(W[(k0 + 3) * NO + nn]);
    hi.x = f32_to_bf16(W[(k0 + 4) * NO + nn]);
    hi.y = f32_to_bf16(W[(k0 + 5) * NO + nn]);
    hi.z = f32_to_bf16(W[(k0 + 6) * NO + nn]);
    hi.w = f32_to_bf16(W[(k0 + 7) * NO + nn]);
    ((ushort4*)&Bp[(size_t)idx * 8])[0] = lo;
    ((ushort4*)&Bp[(size_t)idx * 8])[1] = hi;
}

// ---------------------------------------------------------------------------
// A0: per-chunk LDS bucket histogram -> hists[chunk][256]  (plain stores)
// ---------------------------------------------------------------------------
__device__ void a0_body(int blk, const int* __restrict__ dst, int* __restrict__ hists) {
    __shared__ int h[NBUCK];
    const int t = threadIdx.x;
    h[t] = 0;
    __syncthreads();
    const int lo = blk * BIN_CHUNK;
    const int hi = min(lo + BIN_CHUNK, N_EDGES);
    for (int i = lo + t; i < hi; i += 256) {
        atomicAdd(&h[dst[i] / BUCK_NODES], 1);
    }
    __syncthreads();
    hists[blk * NBUCK + t] = h[t];
}

// ---------------------------------------------------------------------------
// Fused prep: [bucket hists | pack W1 | pack W2]   (cast removed R10)
// ---------------------------------------------------------------------------
__global__ __launch_bounds__(256) void prep_kernel(
        const int* __restrict__ dst, int* __restrict__ hists,
        const float* __restrict__ Ws1, const float* __restrict__ Wn1,
        unsigned short* __restrict__ Bp1,
        const float* __restrict__ Ws2, const float* __restrict__ Wn2,
        unsigned short* __restrict__ Bp2) {
    const int b = blockIdx.x;
    const int t = threadIdx.x;
    if (b < BIN_BLK) {
        a0_body(b, dst, hists);
    } else if (b < BIN_BLK + PACK1_BLK) {
        int idx = (b - BIN_BLK) * 256 + t;
        pack_w_body<256>(idx, Ws1, Wn1, Bp1);
    } else {
        int idx = (b - BIN_BLK - PACK1_BLK) * 256 + t;
        pack_w_body<128>(idx, Ws2, Wn2, Bp2);
    }
}

// ---------------------------------------------------------------------------
// Bucket scan: reduce hists columns + exclusive scan -> bstart[257], bcursor
// ---------------------------------------------------------------------------
__global__ __launch_bounds__(256) void bscan_kernel(const int* __restrict__ hists,
                                                    int* __restrict__ bstart,
                                                    int* __restrict__ bcursor) {
    __shared__ int sc[NBUCK];
    const int t = threadIdx.x;
    int v = 0;
#pragma unroll 8
    for (int c = 0; c < BIN_BLK; ++c) v += hists[c * NBUCK + t];
    sc[t] = v;
    __syncthreads();
    for (int s = 1; s < NBUCK; s <<= 1) {
        int u = (t >= s) ? sc[t - s] : 0;
        __syncthreads();
        sc[t] += u;
        __syncthreads();
    }
    const int excl = sc[t] - v;
    bstart[t] = excl;
    bcursor[t] = excl;
    if (t == NBUCK - 1) bstart[NBUCK] = sc[t];
}

// ---------------------------------------------------------------------------
// A1: bin edges into bucket regions as (dst_local<<16 | src)
// ---------------------------------------------------------------------------
__device__ void a1_body(int blk, const int* __restrict__ src, const int* __restrict__ dst,
                        const int* __restrict__ hists,
                        int* __restrict__ bcursor, unsigned int* __restrict__ binned) {
    __shared__ int base[NBUCK];
    __shared__ int cnt[NBUCK];
    const int t = threadIdx.x;
    const int h = hists[blk * NBUCK + t];
    base[t] = atomicAdd(&bcursor[t], h);
    cnt[t] = 0;
    __syncthreads();
    const int lo = blk * BIN_CHUNK;
    const int hi = min(lo + BIN_CHUNK, N_EDGES);
    for (int i = lo + t; i < hi; i += 256) {
        const int d = dst[i];
        const int b = d / BUCK_NODES;
        const int r = atomicAdd(&cnt[b], 1);
        binned[base[b] + r] = ((unsigned int)(d - b * BUCK_NODES) << 16) | (unsigned int)src[i];
    }
}

// ---------------------------------------------------------------------------
// MFMA dual GEMM body. AF32: A operand read from fp32 (in-register cvt).
// SB16: self-term output bf16 (else fp32). PFP8: p output fp8 (else bf16).
// ---------------------------------------------------------------------------
__device__ __forceinline__ bf16x8 load_a_f32(const float* base) {
    float4 u = ((const float4*)base)[0];
    float4 v = ((const float4*)base)[1];
    bf16x8 a;
    a[0] = (short)f32_to_bf16(u.x); a[1] = (short)f32_to_bf16(u.y);
    a[2] = (short)f32_to_bf16(u.z); a[3] = (short)f32_to_bf16(u.w);
    a[4] = (short)f32_to_bf16(v.x); a[5] = (short)f32_to_bf16(v.y);
    a[6] = (short)f32_to_bf16(v.z); a[7] = (short)f32_to_bf16(v.w);
    return a;
}

template <int NOUT, bool AF32, bool SB16, bool PFP8>
__device__ void gemm_mfma_body(int gblk,
                               const float* __restrict__ af,        // A fp32 (AF32)
                               const unsigned short* __restrict__ ab, // A bf16 (!AF32)
                               const unsigned short* __restrict__ Bp,
                               const float* __restrict__ bias,
                               float* __restrict__ s32,
                               unsigned short* __restrict__ s16,
                               unsigned char* __restrict__ p8,
                               unsigned short* __restrict__ p16) {
    constexpr int NT = NOUT / 16;
    constexpr int NO = NOUT / 2;
    constexpr int NSUB = NT / 4;

    const int tid = threadIdx.x;
    const int wave = tid >> 6;
    const int lane = tid & 63;
    const int mcol = lane & 15;
    const int kgrp = lane >> 4;

    const int mbase = gblk * 32;
    int r0 = mbase + mcol;       if (r0 >= N_NODES) r0 = N_NODES - 1;
    int r1 = mbase + 16 + mcol;  if (r1 >= N_NODES) r1 = N_NODES - 1;

    f32x4 acc[2][NSUB];
#pragma unroll
    for (int mt = 0; mt < 2; ++mt)
#pragma unroll
        for (int c = 0; c < NSUB; ++c)
            acc[mt][c] = (f32x4){0.f, 0.f, 0.f, 0.f};

#pragma unroll
    for (int t = 0; t < 4; ++t) {
        bf16x8 a0, a1;
        if (AF32) {
            a0 = load_a_f32(&af[(size_t)r0 * 128 + t * 32 + kgrp * 8]);
            a1 = load_a_f32(&af[(size_t)r1 * 128 + t * 32 + kgrp * 8]);
        } else {
            a0 = *(const bf16x8*)&ab[(size_t)r0 * 128 + t * 32 + kgrp * 8];
            a1 = *(const bf16x8*)&ab[(size_t)r1 * 128 + t * 32 + kgrp * 8];
        }
#pragma unroll
        for (int c = 0; c < NSUB; ++c) {
            const int ct = wave * NSUB + c;
            bf16x8 bfrag = *(const bf16x8*)&Bp[((size_t)(t * NT + ct) * 64 + lane) * 8];
            acc[0][c] = __builtin_amdgcn_mfma_f32_16x16x32_bf16(a0, bfrag, acc[0][c], 0, 0, 0);
            acc[1][c] = __builtin_amdgcn_mfma_f32_16x16x32_bf16(a1, bfrag, acc[1][c], 0, 0, 0);
        }
    }

    float bv[NSUB];
    int ncols[NSUB];
#pragma unroll
    for (int c = 0; c < NSUB; ++c) {
        ncols[c] = (wave * NSUB + c) * 16 + mcol;
        bv[c] = (ncols[c] < NO) ? bias[ncols[c]] : 0.f;
    }

#pragma unroll
    for (int mt = 0; mt < 2; ++mt) {
#pragma unroll
        for (int c = 0; c < NSUB; ++c) {
            const int ncol = ncols[c];
#pragma unroll
            for (int r = 0; r < 4; ++r) {
                const int node = mbase + mt * 16 + kgrp * 4 + r;
                if (node >= N_NODES) continue;
                const float v = acc[mt][c][r];
                if (ncol < NO) {
                    if (SB16) s16[(size_t)node * NO + ncol] = f32_to_bf16(v + bv[c]);
                    else      s32[(size_t)node * NO + ncol] = v + bv[c];
                } else if (PFP8) {
                    p8[(size_t)node * NO + (ncol - NO)] = f32_to_fp8(v);
                } else {
                    p16[(size_t)node * NO + (ncol - NO)] = f32_to_bf16(v);
                }
            }
        }
    }
}

__global__ __launch_bounds__(256) void bin_gemm1_kernel(
        const int* __restrict__ src, const int* __restrict__ dst,
        const int* __restrict__ hists,
        int* __restrict__ bcursor, unsigned int* __restrict__ binned,
        const float* __restrict__ x,
        const unsigned short* __restrict__ Bp1,
        const float* __restrict__ b1,
        unsigned short* __restrict__ s1, unsigned char* __restrict__ p1) {
    const int b = blockIdx.x;
    if (b < BIN_BLK) {
        a1_body(b, src, dst, hists, bcursor, binned);
    } else {
        gemm_mfma_body<256, true, true, true>(b - BIN_BLK, x, nullptr, Bp1, b1,
                                              nullptr, s1, p1, nullptr);
    }
}

// ---------------------------------------------------------------------------
// Pass B: per-bucket counting sort -> csr16 + offsets (verified R7-R9)
// ---------------------------------------------------------------------------
__global__ __launch_bounds__(256) void bucket_build_kernel(
        const unsigned int* __restrict__ binned,
        const int* __restrict__ bstart,
        int* __restrict__ offsets,
        unsigned short* __restrict__ csr16) {
    __shared__ int cnt[NBUCK];
    __shared__ int pre[NBUCK];
    const int b = blockIdx.x;
    const int t = threadIdx.x;
    const int n0 = b * BUCK_NODES;
    const int nn = min(N_NODES - n0, BUCK_NODES);
    const int e0 = bstart[b];
    const int e1 = bstart[b + 1];

    cnt[t] = 0;
    __syncthreads();
    for (int i = e0 + t; i < e1; i += 256) {
        atomicAdd(&cnt[binned[i] >> 16], 1);
    }
    __syncthreads();
    int v = cnt[t];
    pre[t] = v;
    __syncthreads();
    for (int s = 1; s < NBUCK; s <<= 1) {
        int u = (t >= s) ? pre[t - s] : 0;
        __syncthreads();
        pre[t] += u;
        __syncthreads();
    }
    const int excl = pre[t] - v;
    if (t < nn) offsets[n0 + t] = e0 + excl;
    if (b == 0 && t == 0) offsets[N_NODES] = N_EDGES;
    __syncthreads();
    pre[t] = excl;
    cnt[t] = 0;
    __syncthreads();
    for (int i = e0 + t; i < e1; i += 256) {
        const unsigned int u = binned[i];
        const int dl = (int)(u >> 16);
        const int r = atomicAdd(&cnt[dl], 1);
        csr16[e0 + pre[dl] + r] = (unsigned short)(u & 0xffffu);
    }
}

__global__ __launch_bounds__(256) void gemm2_kernel(
        const unsigned short* __restrict__ h1b,
        const unsigned short* __restrict__ Bp2,
        const float* __restrict__ b2,
        float* __restrict__ s2, unsigned short* __restrict__ p2) {
    gemm_mfma_body<128, false, false, false>(blockIdx.x, nullptr, h1b, Bp2, b2,
                                             s2, nullptr, nullptr, p2);
}

// ---------------------------------------------------------------------------
// Aggregate, F=128, p fp8, s bf16: wave/node, 4 streams x 8 masked neighbors.
// h1b = relu(s + mean gather(p))  (bf16 out)
// ---------------------------------------------------------------------------
__global__ __launch_bounds__(256) void agg_relu_128_kernel(
        const unsigned short* __restrict__ s16,
        const unsigned char* __restrict__ p,
        const int* __restrict__ offsets,
        const unsigned short* __restrict__ csr16,
        unsigned short* __restrict__ h1b) {
    const int wave = threadIdx.x >> 6;
    const int lane = threadIdx.x & 63;
    const int q = lane >> 4;
    const int l = lane & 15;
    const int node = blockIdx.x * 4 + wave;
    if (node >= N_NODES) return;

    const int off0 = offsets[node];
    const int off1 = offsets[node + 1];
    const uint2* pp = (const uint2*)p;   // fp8 row = 16 uint2 (128B)

    float a[8];
#pragma unroll
    for (int k = 0; k < 8; ++k) a[k] = 0.f;

    for (int i = off0 + q; i < off1; i += 32) {
        int idx[8];
        float m[8];
        uint2 w[8];
#pragma unroll
        for (int j = 0; j < 8; ++j) {
            const int e = i + 4 * j;
            const int ec = min(e, off1 - 1);
            idx[j] = (int)csr16[ec];
            m[j] = (e < off1) ? 1.f : 0.f;
        }
#pragma unroll
        for (int j = 0; j < 8; ++j) w[j] = pp[(size_t)idx[j] * 16 + l];
#pragma unroll
        for (int j = 0; j < 8; ++j) {
            float d0[4], d1[4];
            fp8x4_to_f32(w[j].x, d0);
            fp8x4_to_f32(w[j].y, d1);
            a[0] += m[j] * d0[0]; a[1] += m[j] * d0[1];
            a[2] += m[j] * d0[2]; a[3] += m[j] * d0[3];
            a[4] += m[j] * d1[0]; a[5] += m[j] * d1[1];
            a[6] += m[j] * d1[2]; a[7] += m[j] * d1[3];
        }
    }
#pragma unroll
    for (int k = 0; k < 8; ++k) {
        a[k] += __shfl_xor(a[k], 16);
        a[k] += __shfl_xor(a[k], 32);
    }

    if (q == 0) {
        const float invdeg = 1.0f / fmaxf((float)(off1 - off0), 1.0f);
        uint4 sw = ((const uint4*)s16)[(size_t)node * 16 + l];   // 8 bf16 self
        float sf[8];
        sf[0] = bf16lo(sw.x); sf[1] = bf16hi(sw.x);
        sf[2] = bf16lo(sw.y); sf[3] = bf16hi(sw.y);
        sf[4] = bf16lo(sw.z); sf[5] = bf16hi(sw.z);
        sf[6] = bf16lo(sw.w); sf[7] = bf16hi(sw.w);
        ushort4 o0, o1;
        o0.x = f32_to_bf16(fmaxf(sf[0] + a[0] * invdeg, 0.f));
        o0.y = f32_to_bf16(fmaxf(sf[1] + a[1] * invdeg, 0.f));
        o0.z = f32_to_bf16(fmaxf(sf[2] + a[2] * invdeg, 0.f));
        o0.w = f32_to_bf16(fmaxf(sf[3] + a[3] * invdeg, 0.f));
        o1.x = f32_to_bf16(fmaxf(sf[4] + a[4] * invdeg, 0.f));
        o1.y = f32_to_bf16(fmaxf(sf[5] + a[5] * invdeg, 0.f));
        o1.z = f32_to_bf16(fmaxf(sf[6] + a[6] * invdeg, 0.f));
        o1.w = f32_to_bf16(fmaxf(sf[7] + a[7] * invdeg, 0.f));
        ((ushort4*)h1b)[(size_t)node * 32 + l * 2] = o0;
        ((ushort4*)h1b)[(size_t)node * 32 + l * 2 + 1] = o1;
    }
}

// ---------------------------------------------------------------------------
// Aggregate, F=64, p bf16: wave/node, 8 streams x 4 masked neighbors.
// out += mean gather(p)  (fp32 in place)
// ---------------------------------------------------------------------------
__global__ __launch_bounds__(256) void agg_64_kernel(
        const unsigned short* __restrict__ p,
        const int* __restrict__ offsets,
        const unsigned short* __restrict__ csr16,
        float* __restrict__ out) {
    const int wave = threadIdx.x >> 6;
    const int lane = threadIdx.x & 63;
    const int st = lane >> 3;
    const int l = lane & 7;
    const int node = blockIdx.x * 4 + wave;
    if (node >= N_NODES) return;

    const int off0 = offsets[node];
    const int off1 = offsets[node + 1];
    const uint4* pp = (const uint4*)p;   // bf16 row = 8 uint4 (128B)

    float a[8];
#pragma unroll
    for (int k = 0; k < 8; ++k) a[k] = 0.f;

    for (int i = off0 + st; i < off1; i += 32) {
        int idx[4];
        float m[4];
        uint4 w[4];
#pragma unroll
        for (int j = 0; j < 4; ++j) {
            const int e = i + 8 * j;
            const int ec = min(e, off1 - 1);
            idx[j] = (int)csr16[ec];
            m[j] = (e < off1) ? 1.f : 0.f;
        }
#pragma unroll
        for (int j = 0; j < 4; ++j) w[j] = pp[(size_t)idx[j] * 8 + l];
#pragma unroll
        for (int j = 0; j < 4; ++j) {
            a[0] += m[j] * bf16lo(w[j].x); a[1] += m[j] * bf16hi(w[j].x);
            a[2] += m[j] * bf16lo(w[j].y); a[3] += m[j] * bf16hi(w[j].y);
            a[4] += m[j] * bf16lo(w[j].z); a[5] += m[j] * bf16hi(w[j].z);
            a[6] += m[j] * bf16lo(w[j].w); a[7] += m[j] * bf16hi(w[j].w);
        }
    }
#pragma unroll
    for (int k = 0; k < 8; ++k) {
        a[k] += __shfl_xor(a[k], 8);
        a[k] += __shfl_xor(a[k], 16);
        a[k] += __shfl_xor(a[k], 32);
    }

    if (st == 0) {
        const float invdeg = 1.0f / fmaxf((float)(off1 - off0), 1.0f);
        float4 s0 = ((float4*)out)[(size_t)node * 16 + l * 2];
        float4 s1 = ((float4*)out)[(size_t)node * 16 + l * 2 + 1];
        s0.x += a[0] * invdeg; s0.y += a[1] * invdeg;
        s0.z += a[2] * invdeg; s0.w += a[3] * invdeg;
        s1.x += a[4] * invdeg; s1.y += a[5] * invdeg;
        s1.z += a[6] * invdeg; s1.w += a[7] * invdeg;
        ((float4*)out)[(size_t)node * 16 + l * 2] = s0;
        ((float4*)out)[(size_t)node * 16 + l * 2 + 1] = s1;
    }
}

extern "C" void kernel_launch(void* const* d_in, const int* in_sizes, int n_in,
                              void* d_out, int out_size, void* d_ws, size_t ws_size,
                              hipStream_t stream) {
    const float* x        = (const float*)d_in[0];
    const float* W_self1  = (const float*)d_in[1];
    const float* W_neigh1 = (const float*)d_in[2];
    const float* b1       = (const float*)d_in[3];
    const float* W_self2  = (const float*)d_in[4];
    const float* W_neigh2 = (const float*)d_in[5];
    const float* b2       = (const float*)d_in[6];
    const int*   src      = (const int*)d_in[7];
    const int*   dst      = (const int*)d_in[8];
    float* out = (float*)d_out;

    // workspace (4B units)
    int* bstart  = (int*)d_ws;                          // 288 (uses 257)
    int* bcursor = bstart + 288;                        // 256
    int* offsets = bcursor + 256;                       // 50048
    int* hists   = offsets + 50048;                     // 391*256 = 100096
    unsigned int* binned = (unsigned int*)(hists + BIN_BLK * NBUCK);      // 800000
    unsigned short* csr16 = (unsigned short*)(binned + 800000);           // 800000 ushort
    unsigned short* Bp1 = csr16 + 800000;                                  // 32768 bf16
    unsigned short* Bp2 = Bp1 + 32768;                                     // 16384 bf16
    unsigned short* s1  = Bp2 + 16384;                                     // 6.4M bf16 (12.8MB)
    unsigned short* h1b = s1 + (size_t)N_NODES * 128;                      // 6.4M bf16
    unsigned char* p1   = (unsigned char*)(h1b + (size_t)N_NODES * 128);   // 6.4M fp8 (-> p2)
    unsigned short* p2  = (unsigned short*)p1;                             // 3.2M bf16

    prep_kernel<<<PREP_BLK, 256, 0, stream>>>(dst, hists,
                                              W_self1, W_neigh1, Bp1,
                                              W_self2, W_neigh2, Bp2);
    bscan_kernel<<<1, 256, 0, stream>>>(hists, bstart, bcursor);
    bin_gemm1_kernel<<<BG_BLK, 256, 0, stream>>>(src, dst, hists, bcursor, binned,
                                                 x, Bp1, b1, s1, p1);
    bucket_build_kernel<<<NBUCK, 256, 0, stream>>>(binned, bstart, offsets, csr16);
    agg_relu_128_kernel<<<(N_NODES + 3) / 4, 256, 0, stream>>>(s1, p1, offsets, csr16, h1b);
    gemm2_kernel<<<(N_NODES + 31) / 32, 256, 0, stream>>>(h1b, Bp2, b2, out, p2);
    agg_64_kernel<<<(N_NODES + 3) / 4, 256, 0, stream>>>(p2, offsets, csr16, out);
}

// Round 11
// 195.794 us; speedup vs baseline: 1.0624x; 1.0624x over previous
//
#include <hip/hip_runtime.h>
#include <hip/hip_fp16.h>

#define N_NODES 50000
#define N_EDGES 800000
#define N_FEAT 128
#define N_HIDDEN 128
#define N_CLASSES 64

#define NBUCK 512
#define BUCK_NODES 98         // 512*98 = 50176 >= 50000
#define BIN_CHUNK 2048
#define BIN_BLK ((N_EDGES + BIN_CHUNK - 1) / BIN_CHUNK)   // 391

#define PACK1_BLK 16
#define PACK2_BLK 8
#define PREP_BLK (BIN_BLK + PACK1_BLK + PACK2_BLK)        // 415
#define GEMM1_BLK ((N_NODES + 31) / 32)   // 1563
#define BG_BLK (BIN_BLK + GEMM1_BLK)

typedef __attribute__((ext_vector_type(8))) short bf16x8;
typedef __attribute__((ext_vector_type(4))) float f32x4;
typedef __attribute__((ext_vector_type(2))) float f32x2;

__device__ __forceinline__ unsigned short f32_to_bf16(float f) {
    unsigned int u = __float_as_uint(f);
    return (unsigned short)((u + 0x7fffu + ((u >> 16) & 1u)) >> 16);
}
__device__ __forceinline__ float bf16lo(unsigned int v) { return __uint_as_float(v << 16); }
__device__ __forceinline__ float bf16hi(unsigned int v) { return __uint_as_float(v & 0xffff0000u); }

// ---------------- fp8 helpers: HW e4m3 path, e5m2-shift fallback ----------
#if defined(__has_builtin)
#if __has_builtin(__builtin_amdgcn_cvt_pk_f32_fp8) && __has_builtin(__builtin_amdgcn_cvt_pk_fp8_f32)
#define FP8_HW 1
#endif
#endif

__device__ __forceinline__ unsigned char f32_to_fp8(float f) {
#ifdef FP8_HW
    return (unsigned char)(__builtin_amdgcn_cvt_pk_fp8_f32(f, f, 0, false) & 0xff);
#else
    unsigned short hb = __half_as_ushort(__float2half(f));
    return (unsigned char)((hb + 0x7fu + ((hb >> 8) & 1u)) >> 8);
#endif
}

__device__ __forceinline__ void fp8x4_to_f32(unsigned int u, float* o) {
#ifdef FP8_HW
    f32x2 lo = __builtin_amdgcn_cvt_pk_f32_fp8(u, false);
    f32x2 hi = __builtin_amdgcn_cvt_pk_f32_fp8(u, true);
    o[0] = lo.x; o[1] = lo.y; o[2] = hi.x; o[3] = hi.y;
#else
    o[0] = __half2float(__ushort_as_half((unsigned short)((u & 0xffu) << 8)));
    o[1] = __half2float(__ushort_as_half((unsigned short)(((u >> 8) & 0xffu) << 8)));
    o[2] = __half2float(__ushort_as_half((unsigned short)(((u >> 16) & 0xffu) << 8)));
    o[3] = __half2float(__ushort_as_half((unsigned short)(((u >> 24) & 0xffu) << 8)));
#endif
}

// ---------------------------------------------------------------------------
// Pack W helper
// ---------------------------------------------------------------------------
template <int NOUT>
__device__ void pack_w_body(int idx, const float* __restrict__ Wself,
                            const float* __restrict__ Wneigh,
                            unsigned short* __restrict__ Bp) {
    constexpr int NT = NOUT / 16;
    constexpr int NO = NOUT / 2;
    if (idx >= 4 * NT * 64) return;
    const int lane = idx & 63;
    const int tc = idx >> 6;
    const int c = tc % NT;
    const int t = tc / NT;
    const int n = c * 16 + (lane & 15);
    const int k0 = t * 32 + (lane >> 4) * 8;
    const float* W = (n < NO) ? Wself : Wneigh;
    const int nn = (n < NO) ? n : n - NO;
    ushort4 lo, hi;
    lo.x = f32_to_bf16(W[(k0 + 0) * NO + nn]);
    lo.y = f32_to_bf16(W[(k0 + 1) * NO + nn]);
    lo.z = f32_to_bf16(W[(k0 + 2) * NO + nn]);
    lo.w = f32_to_bf16(W[(k0 + 3) * NO + nn]);
    hi.x = f32_to_bf16(W[(k0 + 4) * NO + nn]);
    hi.y = f32_to_bf16(W[(k0 + 5) * NO + nn]);
    hi.z = f32_to_bf16(W[(k0 + 6) * NO + nn]);
    hi.w = f32_to_bf16(W[(k0 + 7) * NO + nn]);
    ((ushort4*)&Bp[(size_t)idx * 8])[0] = lo;
    ((ushort4*)&Bp[(size_t)idx * 8])[1] = hi;
}

// ---------------------------------------------------------------------------
// A0: per-chunk LDS bucket histogram (512 buckets), int4 edge reads
// ---------------------------------------------------------------------------
__device__ void a0_body(int blk, const int* __restrict__ dst, int* __restrict__ hists) {
    __shared__ int h[NBUCK];
    const int t = threadIdx.x;
    h[t] = 0;
    h[t + 256] = 0;
    __syncthreads();
    const int lo = blk * BIN_CHUNK;
    const int hi = min(lo + BIN_CHUNK, N_EDGES);      // hi-lo always multiple of 4
    for (int i4 = (lo >> 2) + t; i4 < (hi >> 2); i4 += 256) {
        int4 d = ((const int4*)dst)[i4];
        atomicAdd(&h[d.x / BUCK_NODES], 1);
        atomicAdd(&h[d.y / BUCK_NODES], 1);
        atomicAdd(&h[d.z / BUCK_NODES], 1);
        atomicAdd(&h[d.w / BUCK_NODES], 1);
    }
    __syncthreads();
    hists[blk * NBUCK + t] = h[t];
    hists[blk * NBUCK + t + 256] = h[t + 256];
}

// ---------------------------------------------------------------------------
// Fused prep: [bucket hists | pack W1 | pack W2]
// ---------------------------------------------------------------------------
__global__ __launch_bounds__(256) void prep_kernel(
        const int* __restrict__ dst, int* __restrict__ hists,
        const float* __restrict__ Ws1, const float* __restrict__ Wn1,
        unsigned short* __restrict__ Bp1,
        const float* __restrict__ Ws2, const float* __restrict__ Wn2,
        unsigned short* __restrict__ Bp2) {
    const int b = blockIdx.x;
    const int t = threadIdx.x;
    if (b < BIN_BLK) {
        a0_body(b, dst, hists);
    } else if (b < BIN_BLK + PACK1_BLK) {
        int idx = (b - BIN_BLK) * 256 + t;
        pack_w_body<256>(idx, Ws1, Wn1, Bp1);
    } else {
        int idx = (b - BIN_BLK - PACK1_BLK) * 256 + t;
        pack_w_body<128>(idx, Ws2, Wn2, Bp2);
    }
}

// ---------------------------------------------------------------------------
// Column sum: block b sums hists[:, b] (391 values) via wave reduce
// ---------------------------------------------------------------------------
__global__ __launch_bounds__(64) void colsum_kernel(const int* __restrict__ hists,
                                                    int* __restrict__ colsum) {
    const int b = blockIdx.x;       // bucket
    const int t = threadIdx.x;      // 0..63
    int v = 0;
    for (int c = t; c < BIN_BLK; c += 64) v += hists[c * NBUCK + b];
#pragma unroll
    for (int s = 32; s > 0; s >>= 1) v += __shfl_down(v, s);
    if (t == 0) colsum[b] = v;
}

// ---------------------------------------------------------------------------
// Bucket scan: exclusive scan of 512 colsums -> bstart[513], bcursor
// ---------------------------------------------------------------------------
__global__ __launch_bounds__(512) void bscan_kernel(const int* __restrict__ colsum,
                                                    int* __restrict__ bstart,
                                                    int* __restrict__ bcursor) {
    __shared__ int sc[NBUCK];
    const int t = threadIdx.x;      // 0..511
    const int v = colsum[t];
    sc[t] = v;
    __syncthreads();
    for (int s = 1; s < NBUCK; s <<= 1) {
        int u = (t >= s) ? sc[t - s] : 0;
        __syncthreads();
        sc[t] += u;
        __syncthreads();
    }
    const int excl = sc[t] - v;
    bstart[t] = excl;
    bcursor[t] = excl;
    if (t == NBUCK - 1) bstart[NBUCK] = sc[t];
}

// ---------------------------------------------------------------------------
// A1: bin edges into bucket regions as (dst_local<<16 | src), int4 reads
// ---------------------------------------------------------------------------
__device__ void a1_body(int blk, const int* __restrict__ src, const int* __restrict__ dst,
                        const int* __restrict__ hists,
                        int* __restrict__ bcursor, unsigned int* __restrict__ binned) {
    __shared__ int base[NBUCK];
    __shared__ int cnt[NBUCK];
    const int t = threadIdx.x;
    {
        const int h0 = hists[blk * NBUCK + t];
        const int h1 = hists[blk * NBUCK + t + 256];
        base[t] = atomicAdd(&bcursor[t], h0);
        base[t + 256] = atomicAdd(&bcursor[t + 256], h1);
        cnt[t] = 0;
        cnt[t + 256] = 0;
    }
    __syncthreads();
    const int lo = blk * BIN_CHUNK;
    const int hi = min(lo + BIN_CHUNK, N_EDGES);
    for (int i4 = (lo >> 2) + t; i4 < (hi >> 2); i4 += 256) {
        int4 d = ((const int4*)dst)[i4];
        int4 s = ((const int4*)src)[i4];
#pragma unroll
        for (int j = 0; j < 4; ++j) {
            const int dj = (j == 0) ? d.x : (j == 1) ? d.y : (j == 2) ? d.z : d.w;
            const int sj = (j == 0) ? s.x : (j == 1) ? s.y : (j == 2) ? s.z : s.w;
            const int b = dj / BUCK_NODES;
            const int r = atomicAdd(&cnt[b], 1);
            binned[base[b] + r] = ((unsigned int)(dj - b * BUCK_NODES) << 16) | (unsigned int)sj;
        }
    }
}

// ---------------------------------------------------------------------------
// MFMA dual GEMM body (verified R5-R10). AF32: A from fp32 in-register cvt.
// SB16: self-term bf16. PFP8: p fp8.
// ---------------------------------------------------------------------------
__device__ __forceinline__ bf16x8 load_a_f32(const float* base) {
    float4 u = ((const float4*)base)[0];
    float4 v = ((const float4*)base)[1];
    bf16x8 a;
    a[0] = (short)f32_to_bf16(u.x); a[1] = (short)f32_to_bf16(u.y);
    a[2] = (short)f32_to_bf16(u.z); a[3] = (short)f32_to_bf16(u.w);
    a[4] = (short)f32_to_bf16(v.x); a[5] = (short)f32_to_bf16(v.y);
    a[6] = (short)f32_to_bf16(v.z); a[7] = (short)f32_to_bf16(v.w);
    return a;
}

template <int NOUT, bool AF32, bool SB16, bool PFP8>
__device__ void gemm_mfma_body(int gblk,
                               const float* __restrict__ af,
                               const unsigned short* __restrict__ ab,
                               const unsigned short* __restrict__ Bp,
                               const float* __restrict__ bias,
                               float* __restrict__ s32,
                               unsigned short* __restrict__ s16,
                               unsigned char* __restrict__ p8,
                               unsigned short* __restrict__ p16) {
    constexpr int NT = NOUT / 16;
    constexpr int NO = NOUT / 2;
    constexpr int NSUB = NT / 4;

    const int tid = threadIdx.x;
    const int wave = tid >> 6;
    const int lane = tid & 63;
    const int mcol = lane & 15;
    const int kgrp = lane >> 4;

    const int mbase = gblk * 32;
    int r0 = mbase + mcol;       if (r0 >= N_NODES) r0 = N_NODES - 1;
    int r1 = mbase + 16 + mcol;  if (r1 >= N_NODES) r1 = N_NODES - 1;

    f32x4 acc[2][NSUB];
#pragma unroll
    for (int mt = 0; mt < 2; ++mt)
#pragma unroll
        for (int c = 0; c < NSUB; ++c)
            acc[mt][c] = (f32x4){0.f, 0.f, 0.f, 0.f};

#pragma unroll
    for (int t = 0; t < 4; ++t) {
        bf16x8 a0, a1;
        if (AF32) {
            a0 = load_a_f32(&af[(size_t)r0 * 128 + t * 32 + kgrp * 8]);
            a1 = load_a_f32(&af[(size_t)r1 * 128 + t * 32 + kgrp * 8]);
        } else {
            a0 = *(const bf16x8*)&ab[(size_t)r0 * 128 + t * 32 + kgrp * 8];
            a1 = *(const bf16x8*)&ab[(size_t)r1 * 128 + t * 32 + kgrp * 8];
        }
#pragma unroll
        for (int c = 0; c < NSUB; ++c) {
            const int ct = wave * NSUB + c;
            bf16x8 bfrag = *(const bf16x8*)&Bp[((size_t)(t * NT + ct) * 64 + lane) * 8];
            acc[0][c] = __builtin_amdgcn_mfma_f32_16x16x32_bf16(a0, bfrag, acc[0][c], 0, 0, 0);
            acc[1][c] = __builtin_amdgcn_mfma_f32_16x16x32_bf16(a1, bfrag, acc[1][c], 0, 0, 0);
        }
    }

    float bv[NSUB];
    int ncols[NSUB];
#pragma unroll
    for (int c = 0; c < NSUB; ++c) {
        ncols[c] = (wave * NSUB + c) * 16 + mcol;
        bv[c] = (ncols[c] < NO) ? bias[ncols[c]] : 0.f;
    }

#pragma unroll
    for (int mt = 0; mt < 2; ++mt) {
#pragma unroll
        for (int c = 0; c < NSUB; ++c) {
            const int ncol = ncols[c];
#pragma unroll
            for (int r = 0; r < 4; ++r) {
                const int node = mbase + mt * 16 + kgrp * 4 + r;
                if (node >= N_NODES) continue;
                const float v = acc[mt][c][r];
                if (ncol < NO) {
                    if (SB16) s16[(size_t)node * NO + ncol] = f32_to_bf16(v + bv[c]);
                    else      s32[(size_t)node * NO + ncol] = v + bv[c];
                } else if (PFP8) {
                    p8[(size_t)node * NO + (ncol - NO)] = f32_to_fp8(v);
                } else {
                    p16[(size_t)node * NO + (ncol - NO)] = f32_to_bf16(v);
                }
            }
        }
    }
}

__global__ __launch_bounds__(256) void bin_gemm1_kernel(
        const int* __restrict__ src, const int* __restrict__ dst,
        const int* __restrict__ hists,
        int* __restrict__ bcursor, unsigned int* __restrict__ binned,
        const float* __restrict__ x,
        const unsigned short* __restrict__ Bp1,
        const float* __restrict__ b1,
        unsigned short* __restrict__ s1, unsigned char* __restrict__ p1) {
    const int b = blockIdx.x;
    if (b < BIN_BLK) {
        a1_body(b, src, dst, hists, bcursor, binned);
    } else {
        gemm_mfma_body<256, true, true, true>(b - BIN_BLK, x, nullptr, Bp1, b1,
                                              nullptr, s1, p1, nullptr);
    }
}

// ---------------------------------------------------------------------------
// Pass B: per-bucket (512) counting sort -> csr16 + offsets
// ---------------------------------------------------------------------------
__global__ __launch_bounds__(256) void bucket_build_kernel(
        const unsigned int* __restrict__ binned,
        const int* __restrict__ bstart,
        int* __restrict__ offsets,
        unsigned short* __restrict__ csr16) {
    __shared__ int cnt[128];
    __shared__ int pre[128];
    const int b = blockIdx.x;
    const int t = threadIdx.x;
    const int n0 = b * BUCK_NODES;
    const int nn = min(N_NODES - n0, BUCK_NODES);   // <= 98
    const int e0 = bstart[b];
    const int e1 = bstart[b + 1];

    if (t < 128) cnt[t] = 0;
    __syncthreads();
    for (int i = e0 + t; i < e1; i += 256) {
        atomicAdd(&cnt[binned[i] >> 16], 1);
    }
    __syncthreads();
    if (t < 128) {
        pre[t] = cnt[t];
    }
    __syncthreads();
    for (int s = 1; s < 128; s <<= 1) {
        int u = (t < 128 && t >= s) ? pre[t - s] : 0;
        __syncthreads();
        if (t < 128) pre[t] += u;
        __syncthreads();
    }
    if (t < 128) {
        const int excl = pre[t] - cnt[t];
        if (t < nn) offsets[n0 + t] = e0 + excl;
        pre[t] = excl;
        cnt[t] = 0;
    }
    if (b == 0 && t == 0) offsets[N_NODES] = N_EDGES;
    __syncthreads();
    for (int i = e0 + t; i < e1; i += 256) {
        const unsigned int u = binned[i];
        const int dl = (int)(u >> 16);
        const int r = atomicAdd(&cnt[dl], 1);
        csr16[e0 + pre[dl] + r] = (unsigned short)(u & 0xffffu);
    }
}

__global__ __launch_bounds__(256) void gemm2_kernel(
        const unsigned short* __restrict__ h1b,
        const unsigned short* __restrict__ Bp2,
        const float* __restrict__ b2,
        float* __restrict__ s2, unsigned short* __restrict__ p2) {
    gemm_mfma_body<128, false, false, false>(blockIdx.x, nullptr, h1b, Bp2, b2,
                                             s2, nullptr, nullptr, p2);
}

// ---------------------------------------------------------------------------
// Aggregate, F=128, p fp8, s bf16 (verified R10)
// ---------------------------------------------------------------------------
__global__ __launch_bounds__(256) void agg_relu_128_kernel(
        const unsigned short* __restrict__ s16,
        const unsigned char* __restrict__ p,
        const int* __restrict__ offsets,
        const unsigned short* __restrict__ csr16,
        unsigned short* __restrict__ h1b) {
    const int wave = threadIdx.x >> 6;
    const int lane = threadIdx.x & 63;
    const int q = lane >> 4;
    const int l = lane & 15;
    const int node = blockIdx.x * 4 + wave;
    if (node >= N_NODES) return;

    const int off0 = offsets[node];
    const int off1 = offsets[node + 1];
    const uint2* pp = (const uint2*)p;   // fp8 row = 16 uint2 (128B)

    float a[8];
#pragma unroll
    for (int k = 0; k < 8; ++k) a[k] = 0.f;

    for (int i = off0 + q; i < off1; i += 32) {
        int idx[8];
        float m[8];
        uint2 w[8];
#pragma unroll
        for (int j = 0; j < 8; ++j) {
            const int e = i + 4 * j;
            const int ec = min(e, off1 - 1);
            idx[j] = (int)csr16[ec];
            m[j] = (e < off1) ? 1.f : 0.f;
        }
#pragma unroll
        for (int j = 0; j < 8; ++j) w[j] = pp[(size_t)idx[j] * 16 + l];
#pragma unroll
        for (int j = 0; j < 8; ++j) {
            float d0[4], d1[4];
            fp8x4_to_f32(w[j].x, d0);
            fp8x4_to_f32(w[j].y, d1);
            a[0] += m[j] * d0[0]; a[1] += m[j] * d0[1];
            a[2] += m[j] * d0[2]; a[3] += m[j] * d0[3];
            a[4] += m[j] * d1[0]; a[5] += m[j] * d1[1];
            a[6] += m[j] * d1[2]; a[7] += m[j] * d1[3];
        }
    }
#pragma unroll
    for (int k = 0; k < 8; ++k) {
        a[k] += __shfl_xor(a[k], 16);
        a[k] += __shfl_xor(a[k], 32);
    }

    if (q == 0) {
        const float invdeg = 1.0f / fmaxf((float)(off1 - off0), 1.0f);
        uint4 sw = ((const uint4*)s16)[(size_t)node * 16 + l];
        float sf[8];
        sf[0] = bf16lo(sw.x); sf[1] = bf16hi(sw.x);
        sf[2] = bf16lo(sw.y); sf[3] = bf16hi(sw.y);
        sf[4] = bf16lo(sw.z); sf[5] = bf16hi(sw.z);
        sf[6] = bf16lo(sw.w); sf[7] = bf16hi(sw.w);
        ushort4 o0, o1;
        o0.x = f32_to_bf16(fmaxf(sf[0] + a[0] * invdeg, 0.f));
        o0.y = f32_to_bf16(fmaxf(sf[1] + a[1] * invdeg, 0.f));
        o0.z = f32_to_bf16(fmaxf(sf[2] + a[2] * invdeg, 0.f));
        o0.w = f32_to_bf16(fmaxf(sf[3] + a[3] * invdeg, 0.f));
        o1.x = f32_to_bf16(fmaxf(sf[4] + a[4] * invdeg, 0.f));
        o1.y = f32_to_bf16(fmaxf(sf[5] + a[5] * invdeg, 0.f));
        o1.z = f32_to_bf16(fmaxf(sf[6] + a[6] * invdeg, 0.f));
        o1.w = f32_to_bf16(fmaxf(sf[7] + a[7] * invdeg, 0.f));
        ((ushort4*)h1b)[(size_t)node * 32 + l * 2] = o0;
        ((ushort4*)h1b)[(size_t)node * 32 + l * 2 + 1] = o1;
    }
}

// ---------------------------------------------------------------------------
// Aggregate, F=64, p bf16 (verified R10)
// ---------------------------------------------------------------------------
__global__ __launch_bounds__(256) void agg_64_kernel(
        const unsigned short* __restrict__ p,
        const int* __restrict__ offsets,
        const unsigned short* __restrict__ csr16,
        float* __restrict__ out) {
    const int wave = threadIdx.x >> 6;
    const int lane = threadIdx.x & 63;
    const int st = lane >> 3;
    const int l = lane & 7;
    const int node = blockIdx.x * 4 + wave;
    if (node >= N_NODES) return;

    const int off0 = offsets[node];
    const int off1 = offsets[node + 1];
    const uint4* pp = (const uint4*)p;   // bf16 row = 8 uint4 (128B)

    float a[8];
#pragma unroll
    for (int k = 0; k < 8; ++k) a[k] = 0.f;

    for (int i = off0 + st; i < off1; i += 32) {
        int idx[4];
        float m[4];
        uint4 w[4];
#pragma unroll
        for (int j = 0; j < 4; ++j) {
            const int e = i + 8 * j;
            const int ec = min(e, off1 - 1);
            idx[j] = (int)csr16[ec];
            m[j] = (e < off1) ? 1.f : 0.f;
        }
#pragma unroll
        for (int j = 0; j < 4; ++j) w[j] = pp[(size_t)idx[j] * 8 + l];
#pragma unroll
        for (int j = 0; j < 4; ++j) {
            a[0] += m[j] * bf16lo(w[j].x); a[1] += m[j] * bf16hi(w[j].x);
            a[2] += m[j] * bf16lo(w[j].y); a[3] += m[j] * bf16hi(w[j].y);
            a[4] += m[j] * bf16lo(w[j].z); a[5] += m[j] * bf16hi(w[j].z);
            a[6] += m[j] * bf16lo(w[j].w); a[7] += m[j] * bf16hi(w[j].w);
        }
    }
#pragma unroll
    for (int k = 0; k < 8; ++k) {
        a[k] += __shfl_xor(a[k], 8);
        a[k] += __shfl_xor(a[k], 16);
        a[k] += __shfl_xor(a[k], 32);
    }

    if (st == 0) {
        const float invdeg = 1.0f / fmaxf((float)(off1 - off0), 1.0f);
        float4 s0 = ((float4*)out)[(size_t)node * 16 + l * 2];
        float4 s1 = ((float4*)out)[(size_t)node * 16 + l * 2 + 1];
        s0.x += a[0] * invdeg; s0.y += a[1] * invdeg;
        s0.z += a[2] * invdeg; s0.w += a[3] * invdeg;
        s1.x += a[4] * invdeg; s1.y += a[5] * invdeg;
        s1.z += a[6] * invdeg; s1.w += a[7] * invdeg;
        ((float4*)out)[(size_t)node * 16 + l * 2] = s0;
        ((float4*)out)[(size_t)node * 16 + l * 2 + 1] = s1;
    }
}

extern "C" void kernel_launch(void* const* d_in, const int* in_sizes, int n_in,
                              void* d_out, int out_size, void* d_ws, size_t ws_size,
                              hipStream_t stream) {
    const float* x        = (const float*)d_in[0];
    const float* W_self1  = (const float*)d_in[1];
    const float* W_neigh1 = (const float*)d_in[2];
    const float* b1       = (const float*)d_in[3];
    const float* W_self2  = (const float*)d_in[4];
    const float* W_neigh2 = (const float*)d_in[5];
    const float* b2       = (const float*)d_in[6];
    const int*   src      = (const int*)d_in[7];
    const int*   dst      = (const int*)d_in[8];
    float* out = (float*)d_out;

    // workspace (4B units)
    int* bstart  = (int*)d_ws;                          // 544 (uses 513)
    int* bcursor = bstart + 544;                        // 512
    int* colsum  = bcursor + 512;                       // 512
    int* offsets = colsum + 512;                        // 50048
    int* hists   = offsets + 50048;                     // 391*512 = 200192
    unsigned int* binned = (unsigned int*)(hists + BIN_BLK * NBUCK);      // 800000
    unsigned short* csr16 = (unsigned short*)(binned + 800000);           // 800000 ushort
    unsigned short* Bp1 = csr16 + 800000;                                  // 32768 bf16
    unsigned short* Bp2 = Bp1 + 32768;                                     // 16384 bf16
    unsigned short* s1  = Bp2 + 16384;                                     // 6.4M bf16
    unsigned short* h1b = s1 + (size_t)N_NODES * 128;                      // 6.4M bf16
    unsigned char* p1   = (unsigned char*)(h1b + (size_t)N_NODES * 128);   // 6.4M fp8 (-> p2)
    unsigned short* p2  = (unsigned short*)p1;                             // 3.2M bf16

    prep_kernel<<<PREP_BLK, 256, 0, stream>>>(dst, hists,
                                              W_self1, W_neigh1, Bp1,
                                              W_self2, W_neigh2, Bp2);
    colsum_kernel<<<NBUCK, 64, 0, stream>>>(hists, colsum);
    bscan_kernel<<<1, NBUCK, 0, stream>>>(colsum, bstart, bcursor);
    bin_gemm1_kernel<<<BG_BLK, 256, 0, stream>>>(src, dst, hists, bcursor, binned,
                                                 x, Bp1, b1, s1, p1);
    bucket_build_kernel<<<NBUCK, 256, 0, stream>>>(binned, bstart, offsets, csr16);
    agg_relu_128_kernel<<<(N_NODES + 3) / 4, 256, 0, stream>>>(s1, p1, offsets, csr16, h1b);
    gemm2_kernel<<<(N_NODES + 31) / 32, 256, 0, stream>>>(h1b, Bp2, b2, out, p2);
    agg_64_kernel<<<(N_NODES + 3) / 4, 256, 0, stream>>>(p2, offsets, csr16, out);
}